// Round 4
// baseline (4002.094 us; speedup 1.0000x reference)
//
#include <hip/hip_runtime.h>
#include <math.h>

#define L_SEQ 1024
#define WIN   32
#define CDIM  144
#define NW    993            // (1024-32)/1 + 1
#define HDIM  512
#define RDIM  256
#define M_ROWS (NW*CDIM)     // 142992
#define TILE_M 8
#define NBLK  (M_ROWS/TILE_M) // 17874
#define SLOPE 0.1

__device__ __forceinline__ double dlrelu(double x){ return x >= 0.0 ? x : SLOPE*x; }

// ---------------- prologue: axis-angle -> 6D (fp64 math) ----------------
__global__ void k_prep(const float* __restrict__ dp, float* __restrict__ d6){
  int idx = blockIdx.x*256 + threadIdx.x;
  if (idx >= L_SEQ*24) return;
  int l = idx / 24, j = idx % 24;
  const float* a = dp + l*72 + j*3;
  double x = (double)a[0], y = (double)a[1], z = (double)a[2];
  double ang = sqrt(x*x + y*y + z*z);
  double inv = 1.0 / fmax(ang, 1e-8);
  double ax = x*inv, ay = y*inv, az = z*inv;
  double s = sin(ang), c = cos(ang), C = 1.0 - c;
  float* o = d6 + l*CDIM + j*6;
  o[0] = (float)(c + ax*ax*C);
  o[1] = (float)(ax*ay*C - az*s);
  o[2] = (float)(ax*az*C + ay*s);
  o[3] = (float)(ay*ax*C + az*s);
  o[4] = (float)(c + ay*ay*C);
  o[5] = (float)(ay*az*C - ax*s);
}

// ---------------- weight transpose (fp32) ----------------
__global__ void k_transpose(const float* __restrict__ src, float* __restrict__ dst,
                            int R, int C){
  int idx = blockIdx.x*256 + threadIdx.x;
  if (idx >= R*C) return;
  int r = idx / C, c = idx % C;
  dst[c*R + r] = src[idx];
}

// ---------------- fused MLP ----------------
// Activations live in LDS as fp64 (value == fp32-rounded, upconverted), laid
// out [k][r] with r-stride TILE_M=8 -> per-k act reads are wave-uniform
// broadcast ds_read_b128. Weights fp32 (pre-transposed in ws), one cvt per
// column per k amortized over 8/4 rows of v_fma_f64.
// Numerics: bit-identical to the round-2 passing kernel (same per-element
// fp64 fma chains in k order; activations rounded through fp32 before store;
// residual adds performed in fp32).

// Mid layer: KD -> JD.
//   JD==512: each thread owns cols {tid, tid+256}, rows 0..7.
//   JD==256: each thread owns cols {tid&127, (tid&127)+128}, rows (tid>>7)*4 ..+3.
template<int KD, int JD, bool RES>
__device__ __forceinline__ void layerD(const double* S, double* D,
                                       const float* __restrict__ Wt,
                                       const float* __restrict__ bias, int tid){
  constexpr int CS = JD/2;
  constexpr int R  = (JD==512) ? 8 : 4;
  const int cg    = (JD==512) ? tid : (tid & 127);
  const int rbase = (JD==512) ? 0   : ((tid >> 7) * 4);
  double acc0[R], acc1[R];
  #pragma unroll
  for (int r = 0; r < R; ++r){ acc0[r]=0.0; acc1[r]=0.0; }

  #pragma unroll 4
  for (int k = 0; k < KD; ++k){
    const double* sp = S + k*TILE_M + rbase;
    double a[R];
    #pragma unroll
    for (int i = 0; i < R; i += 2){
      double2 v = *(const double2*)(sp + i);
      a[i] = v.x; a[i+1] = v.y;
    }
    double w0 = (double)Wt[k*JD + cg];
    double w1 = (double)Wt[k*JD + cg + CS];
    #pragma unroll
    for (int r = 0; r < R; ++r){
      acc0[r] = fma(a[r], w0, acc0[r]);
      acc1[r] = fma(a[r], w1, acc1[r]);
    }
  }

  double b0 = (double)bias[cg], b1 = (double)bias[cg + CS];
  double* d0 = D + (size_t)cg*TILE_M + rbase;
  double* d1 = D + (size_t)(cg+CS)*TILE_M + rbase;
  #pragma unroll
  for (int r = 0; r < R; ++r){
    float v0 = (float)dlrelu(acc0[r] + b0);
    float v1 = (float)dlrelu(acc1[r] + b1);
    if (RES){
      float h0 = (float)d0[r] + v0;   // fp32 residual add (matches reference chain)
      float h1 = (float)d1[r] + v1;
      d0[r] = (double)h0; d1[r] = (double)h1;
    } else {
      d0[r] = (double)v0; d1[r] = (double)v1;
    }
  }
}

__global__ __launch_bounds__(256, 3) void k_mlp(
    const float* __restrict__ d6,
    const float* __restrict__ w_inT, const float* __restrict__ b_in,
    const float* __restrict__ w1aT, const float* __restrict__ b1a,
    const float* __restrict__ w1bT, const float* __restrict__ b1b,
    const float* __restrict__ w2aT, const float* __restrict__ b2a,
    const float* __restrict__ w2bT, const float* __restrict__ b2b,
    const float* __restrict__ w_outT, const float* __restrict__ b_out,
    float* __restrict__ y)
{
  __shared__ __align__(16) double hb[HDIM*TILE_M];   // 32 KiB, [k][r]
  __shared__ __align__(16) double rb[RDIM*TILE_M];   // 16 KiB, [k][r]; xb overlays
  const int tid = threadIdx.x;
  const int m0  = blockIdx.x * TILE_M;

  // gather input windows into xb (= rb[0..255]): xb[t*8 + r] = d6[(n+t)*144 + c]
  {
    int r = tid & 7, t = tid >> 3;       // t in 0..31
    int m = m0 + r;
    int n = m / CDIM, c = m % CDIM;
    rb[t*TILE_M + r] = (double)d6[(n+t)*CDIM + c];
  }
  __syncthreads();

  // ---- L_in: 32 -> 512 (reads xb in rb, writes hb) ----
  {
    const int j0 = tid, j1 = tid + 256;
    double acc0[8], acc1[8];
    #pragma unroll
    for (int r = 0; r < 8; ++r){ acc0[r]=0.0; acc1[r]=0.0; }
    #pragma unroll 4
    for (int k = 0; k < WIN; ++k){
      const double* sp = rb + k*TILE_M;
      double a[8];
      #pragma unroll
      for (int i = 0; i < 8; i += 2){
        double2 v = *(const double2*)(sp + i);
        a[i] = v.x; a[i+1] = v.y;
      }
      double w0 = (double)w_inT[k*HDIM + j0];
      double w1 = (double)w_inT[k*HDIM + j1];
      #pragma unroll
      for (int r = 0; r < 8; ++r){
        acc0[r] = fma(a[r], w0, acc0[r]);
        acc1[r] = fma(a[r], w1, acc1[r]);
      }
    }
    double bb0 = (double)b_in[j0], bb1 = (double)b_in[j1];
    #pragma unroll
    for (int r = 0; r < 8; ++r){
      hb[j0*TILE_M + r] = (double)(float)dlrelu(acc0[r] + bb0);
      hb[j1*TILE_M + r] = (double)(float)dlrelu(acc1[r] + bb1);
    }
  }
  __syncthreads();

  layerD<HDIM, RDIM, false>(hb, rb, w1aT, b1a, tid);  __syncthreads();
  layerD<RDIM, HDIM, true >(rb, hb, w1bT, b1b, tid);  __syncthreads();
  layerD<HDIM, RDIM, false>(hb, rb, w2aT, b2a, tid);  __syncthreads();
  layerD<RDIM, HDIM, true >(rb, hb, w2bT, b2b, tid);  __syncthreads();

  // ---- L_out: 512 -> 32, one (row, t) per thread ----
  {
    const int r  = tid & 7;
    const int th = tid >> 3;             // 0..31
    double o = 0.0;
    #pragma unroll 8
    for (int k = 0; k < HDIM; ++k)
      o = fma(hb[k*TILE_M + r], (double)w_outT[k*32 + th], o);
    int m = m0 + r;
    int n = m / CDIM, c = m % CDIM;
    y[(size_t)th*M_ROWS + n*CDIM + c] = (float)(o + (double)b_out[th]);
  }
}

// ---------------- overlap-average scatter (fp64 sum) ----------------
__global__ void k_scatter(const float* __restrict__ y, float* __restrict__ seq){
  int idx = blockIdx.x*256 + threadIdx.x;
  if (idx >= L_SEQ*CDIM) return;
  int t = idx / CDIM, c = idx % CDIM;
  int nlo = t - (WIN-1); if (nlo < 0) nlo = 0;
  int nhi = t; if (nhi > NW-1) nhi = NW-1;
  double s = 0.0;
  for (int n = nlo; n <= nhi; ++n)
    s += (double)y[(size_t)(t-n)*M_ROWS + n*CDIM + c];
  seq[idx] = (float)(s / (double)(nhi - nlo + 1));
}

// ---------------- epilogue: 6D -> axis-angle (fp64 math) ----------------
__global__ void k_post(const float* __restrict__ seq, float* __restrict__ out){
  int idx = blockIdx.x*256 + threadIdx.x;
  if (idx >= L_SEQ*24) return;
  int t = idx / 24, j = idx % 24;
  const float* s = seq + t*CDIM + j*6;
  double a1x=(double)s[0], a1y=(double)s[1], a1z=(double)s[2];
  double a2x=(double)s[3], a2y=(double)s[4], a2z=(double)s[5];
  double n1 = sqrt(a1x*a1x + a1y*a1y + a1z*a1z);
  double i1 = 1.0 / fmax(n1, 1e-8);
  double b1x=a1x*i1, b1y=a1y*i1, b1z=a1z*i1;
  double d  = b1x*a2x + b1y*a2y + b1z*a2z;
  double px = a2x - d*b1x, py = a2y - d*b1y, pz = a2z - d*b1z;
  double n2 = sqrt(px*px + py*py + pz*pz);
  double i2 = 1.0 / fmax(n2, 1e-8);
  double b2x=px*i2, b2y=py*i2, b2z=pz*i2;
  double b3x = b1y*b2z - b1z*b2y;
  double b3y = b1z*b2x - b1x*b2z;
  double b3z = b1x*b2y - b1y*b2x;
  double tr = b1x + b2y + b3z;
  double cs = fmin(fmax((tr-1.0)*0.5, -1.0+1e-6), 1.0-1e-6);
  double ang = acos(cs);
  double sn  = sqrt(fmax(1.0 - cs*cs, 1e-12));
  double vx = b3y - b2z, vy = b1z - b3x, vz = b2x - b1y;
  double f = ang / (2.0 * sn);
  float* o = out + t*72 + j*3;
  o[0] = (float)(vx*f); o[1] = (float)(vy*f); o[2] = (float)(vz*f);
}

// ---------------- launcher ----------------
extern "C" void kernel_launch(void* const* d_in, const int* in_sizes, int n_in,
                              void* d_out, int out_size, void* d_ws, size_t ws_size,
                              hipStream_t stream) {
  const float* dp    = (const float*)d_in[0];
  const float* w_in  = (const float*)d_in[1];
  const float* b_in  = (const float*)d_in[2];
  const float* w1a   = (const float*)d_in[3];
  const float* b1a   = (const float*)d_in[4];
  const float* w1b   = (const float*)d_in[5];
  const float* b1b   = (const float*)d_in[6];
  const float* w2a   = (const float*)d_in[7];
  const float* b2a   = (const float*)d_in[8];
  const float* w2b   = (const float*)d_in[9];
  const float* b2b   = (const float*)d_in[10];
  const float* w_out = (const float*)d_in[11];
  const float* b_out = (const float*)d_in[12];
  float* out = (float*)d_out;

  float* d6    = (float*)d_ws;             // 1024*144            = 147456
  float* winT  = d6    + 147456;           // 32*512              = 16384
  float* w1aT  = winT  + 16384;            // 512*256             = 131072
  float* w1bT  = w1aT  + 131072;           // 256*512             = 131072
  float* w2aT  = w1bT  + 131072;
  float* w2bT  = w2aT  + 131072;
  float* woutT = w2bT  + 131072;           // 512*32              = 16384
  float* ybuf  = woutT + 16384;            // 32*993*144          = 4575744
  float* seq   = ybuf  + (size_t)WIN*NW*CDIM; // 147456

  k_prep<<<(L_SEQ*24 + 255)/256, 256, 0, stream>>>(dp, d6);

  k_transpose<<<(512*32  + 255)/256, 256, 0, stream>>>(w_in,  winT,  512, 32);
  k_transpose<<<(256*512 + 255)/256, 256, 0, stream>>>(w1a,   w1aT,  256, 512);
  k_transpose<<<(512*256 + 255)/256, 256, 0, stream>>>(w1b,   w1bT,  512, 256);
  k_transpose<<<(256*512 + 255)/256, 256, 0, stream>>>(w2a,   w2aT,  256, 512);
  k_transpose<<<(512*256 + 255)/256, 256, 0, stream>>>(w2b,   w2bT,  512, 256);
  k_transpose<<<(32*512  + 255)/256, 256, 0, stream>>>(w_out, woutT, 32, 512);

  k_mlp<<<NBLK, 256, 0, stream>>>(d6,
      winT, b_in, w1aT, b1a, w1bT, b1b, w2aT, b2a, w2bT, b2b, woutT, b_out,
      ybuf);

  k_scatter<<<(L_SEQ*CDIM + 255)/256, 256, 0, stream>>>(ybuf, seq);
  k_post<<<(L_SEQ*24 + 255)/256, 256, 0, stream>>>(seq, out);
}